// Round 18
// baseline (51.991 us; speedup 1.0000x reference)
//
#include <hip/hip_runtime.h>
#include <math.h>

#define NDET 16
#define NDIM 16

// ---- quad (4-lane) DPP broadcast: pure VALU, no LDS path -----------------
template<int OWNER>
__device__ __forceinline__ float bcast4f(float v) {
    constexpr int ctrl = OWNER * 0x55;  // quad_perm:[OWNER]*4
    return __int_as_float(
        __builtin_amdgcn_mov_dpp(__float_as_int(v), ctrl, 0xF, 0xF, true));
}

// ---- Householder QR step, COLUMN-INVOLUTION ORDER (R11/R13-verbatim) ------
template<int K>
__device__ __forceinline__ void qr_step(float (&c)[4][16], float &prod, float &sgn) {
    constexpr int OWNER = K & 3;
    constexpr int LC    = K >> 2;
    constexpr int JMIN  = K >> 2;

    float s0 = 0.0f, s1 = 0.0f;
    #pragma unroll
    for (int i = K; i < 16; i += 2)     s0 = fmaf(c[LC][i], c[LC][i], s0);
    #pragma unroll
    for (int i = K + 1; i < 16; i += 2) s1 = fmaf(c[LC][i], c[LC][i], s1);

    const float n2    = bcast4f<OWNER>(s0 + s1);
    const float xK    = bcast4f<OWNER>(c[LC][K]);
    const float alpha = __builtin_amdgcn_sqrtf(n2);          // ||x|| > 0 a.s.
    const float vK    = xK + copysignf(alpha, xK);           // |vK| = alpha+|xK|
    const float beta  = __builtin_amdgcn_rcpf(alpha * fabsf(vK));
    prod *= alpha;
    sgn = (xK < 0.0f) ? -sgn : sgn;

    float bv[16];
    bv[K] = vK;
    #pragma unroll
    for (int i = K + 1; i < 16; ++i) bv[i] = bcast4f<OWNER>(c[LC][i]);

    #pragma unroll
    for (int j = JMIN; j < 4; ++j) {
        float w0 = bv[K] * c[j][K], w1 = 0.0f;
        #pragma unroll
        for (int i = K + 1; i < 16; i += 2) w0 = fmaf(bv[i], c[j][i], w0);
        #pragma unroll
        for (int i = K + 2; i < 16; i += 2) w1 = fmaf(bv[i], c[j][i], w1);
        const float t = (w0 + w1) * beta;
        #pragma unroll
        for (int i = K; i < 16; ++i)
            c[j][i] = fmaf(-t, bv[i], c[j][i]);
    }
}

template<int K>
__device__ __forceinline__ void qr_all(float (&c)[4][16], float &prod, float &sgn) {
    qr_step<K>(c, prod, sgn);
    if constexpr (K < 14) qr_all<K + 1>(c, prod, sgn);
}

// Lane-spec shell (R13) + BULK ASYNC DMA STAGING:
// all 64 matrices of the block (64 KB) are staged global->LDS with
// global_load_lds dwordx4 (no VGPR round-trip, off the VALU path), then QR
// reads from LDS. 64 KB LDS -> 2 blocks/CU co-resident, so one block's DMA
// phase overlaps the other's compute phase (the overlap that per-wave
// register prefetch failed to produce in R15/R16).
// Bank-conflict fix: matrix q is staged with 16B column-blocks permuted by
// cb ^= (q&3) (pre-swizzled GLOBAL source, linear LDS dest — the only legal
// swizzle with global_load_lds); read-back XORs the same -> 4-way max.
__global__ __launch_bounds__(256) void logabssumdet_kernel(
    const float* __restrict__ a,
    const float* __restrict__ b,
    const float* __restrict__ w,
    float* __restrict__ out,
    int n_samples)
{
    const int tid    = threadIdx.x;
    const int lane4  = tid & 3;
    const int quad   = tid >> 2;                    // 0..63 in block
    const int half   = quad & 1;                    // 0 -> A, 1 -> B
    const int det_l  = quad >> 1;                   // 0..31 local det index
    const int mat_id = blockIdx.x * 32 + det_l;     // = sample*16 + det
    const int n_mats = n_samples * NDET;

    __shared__ float lds[16384];    // 64 KB: 64 quad-regions x 1 KB
                                    // (aliased as sx[64], ss[64] after compute)

    // ---- cooperative DMA staging: wave w stages quad-slot q = it*4 + w ----
    {
        const int wave = tid >> 6;
        const int lane = tid & 63;
        const int r    = lane >> 2;                 // matrix row 0..15
        #pragma unroll 1
        for (int it = 0; it < 16; ++it) {
            const int q  = it * 4 + wave;           // destination quad-slot
            const int qh = q & 1;
            int qm = blockIdx.x * 32 + (q >> 1);
            if (qm >= n_mats) qm = n_mats - 1;      // clamp (redundant load)
            const int cb = (lane & 3) ^ (q & 3);    // pre-swizzled col block
            const float* gp = (qh ? b : a) + (size_t)qm * 256 + r * 16 + cb * 4;
            __builtin_amdgcn_global_load_lds(
                (const __attribute__((address_space(1))) unsigned int*)gp,
                (__attribute__((address_space(3))) unsigned int*)(lds + q * 256 + lane * 4),
                16, 0, 0);
        }
        asm volatile("s_waitcnt vmcnt(0)" ::: "memory");
        __syncthreads();
    }

    // ---- QR from LDS (R13-verbatim math) -----------------------------------
    float x = 0.0f, sgn = 1.0f;

    if (mat_id < n_mats) {
        const int swz = quad & 3;
        const float4* lq =
            reinterpret_cast<const float4*>(lds) + quad * 64 + (lane4 ^ swz);

        float c[4][16];
        #pragma unroll
        for (int i = 0; i < 16; ++i) {
            const float4 v = lq[i * 4];             // ds_read_b128, <=4-way bank
            c[0][i] = v.x; c[1][i] = v.y; c[2][i] = v.z; c[3][i] = v.w;
        }

        float prod = 1.0f;                          // product of alpha_K (>0)
        qr_all<0>(c, prod, sgn);                    // 15 reflections
        prod *= bcast4f<3>(c[3][15]);               // column perm(15)=15 remainder

        x = __logf(fabsf(prod));                    // f32-range safe (proven)
        sgn = (prod < 0.0f) ? -sgn : sgn;
    }

    __syncthreads();    // all LDS matrix reads done -> safe to alias regions
    if (lane4 == 0) { lds[quad] = x; lds[64 + quad] = sgn; }
    __syncthreads();

    // 2 samples per block; one thread finishes each sample's 16-det LSE
    if (tid < 2) {
        const int sample = blockIdx.x * 2 + tid;
        if (sample < n_samples) {
            const int base = tid * 2 * NDET;        // 32 quad entries per sample
            float xs[NDET];
            float gs[NDET];
            float xmax = -INFINITY;
            #pragma unroll
            for (int d = 0; d < NDET; ++d) {
                xs[d] = lds[base + 2 * d] + lds[base + 2 * d + 1];
                gs[d] = lds[64 + base + 2 * d] * lds[64 + base + 2 * d + 1];
                xmax  = fmaxf(xmax, xs[d]);
            }
            float sum = 0.0f;
            #pragma unroll
            for (int d = 0; d < NDET; ++d)
                sum += gs[d] * __expf(xs[d] - xmax) * w[d];
            out[sample] = __logf(fabsf(sum)) + xmax;
            out[n_samples + sample] = (sum > 0.0f) ? 1.0f : ((sum < 0.0f) ? -1.0f : 0.0f);
        }
    }
}

extern "C" void kernel_launch(void* const* d_in, const int* in_sizes, int n_in,
                              void* d_out, int out_size, void* d_ws, size_t ws_size,
                              hipStream_t stream)
{
    const float* a = (const float*)d_in[0];
    const float* b = (const float*)d_in[1];
    const float* w = (const float*)d_in[2];
    float* out = (float*)d_out;

    const int n_samples = in_sizes[0] / (NDET * NDIM * NDIM);
    const int blocks = (n_samples + 1) / 2;   // 2 samples (64 matrices) per block
    logabssumdet_kernel<<<blocks, 256, 0, stream>>>(a, b, w, out, n_samples);
}

// Round 19
// 48.492 us; speedup vs baseline: 1.0721x; 1.0721x over previous
//
#include <hip/hip_runtime.h>
#include <math.h>

#define NDET 16
#define NDIM 16

// ---- quad (4-lane) DPP broadcast: pure VALU, no LDS path -----------------
template<int OWNER>
__device__ __forceinline__ float bcast4f(float v) {
    constexpr int ctrl = OWNER * 0x55;  // quad_perm:[OWNER]*4
    return __int_as_float(
        __builtin_amdgcn_mov_dpp(__float_as_int(v), ctrl, 0xF, 0xF, true));
}

// ---- Householder QR step, COLUMN-INVOLUTION ORDER (R11-verbatim math) -----
// Step K eliminates global column perm(K)=((K&3)<<2)|(K>>2); owner lane = K&3,
// local col = K>>2; local cols j < K>>2 retired on every lane.
template<int K>
__device__ __forceinline__ void qr_step(float (&c)[4][16], float &prod, float &sgn) {
    constexpr int OWNER = K & 3;
    constexpr int LC    = K >> 2;
    constexpr int JMIN  = K >> 2;

    float s0 = 0.0f, s1 = 0.0f;
    #pragma unroll
    for (int i = K; i < 16; i += 2)     s0 = fmaf(c[LC][i], c[LC][i], s0);
    #pragma unroll
    for (int i = K + 1; i < 16; i += 2) s1 = fmaf(c[LC][i], c[LC][i], s1);

    const float n2    = bcast4f<OWNER>(s0 + s1);
    const float xK    = bcast4f<OWNER>(c[LC][K]);
    const float alpha = __builtin_amdgcn_sqrtf(n2);          // ||x|| > 0 a.s.
    const float vK    = xK + copysignf(alpha, xK);           // |vK| = alpha+|xK|
    const float beta  = __builtin_amdgcn_rcpf(alpha * fabsf(vK));
    prod *= alpha;
    sgn = (xK < 0.0f) ? -sgn : sgn;

    float bv[16];
    bv[K] = vK;
    #pragma unroll
    for (int i = K + 1; i < 16; ++i) bv[i] = bcast4f<OWNER>(c[LC][i]);

    #pragma unroll
    for (int j = JMIN; j < 4; ++j) {
        float w0 = bv[K] * c[j][K], w1 = 0.0f;
        #pragma unroll
        for (int i = K + 1; i < 16; i += 2) w0 = fmaf(bv[i], c[j][i], w0);
        #pragma unroll
        for (int i = K + 2; i < 16; i += 2) w1 = fmaf(bv[i], c[j][i], w1);
        const float t = (w0 + w1) * beta;
        #pragma unroll
        for (int i = K; i < 16; ++i)
            c[j][i] = fmaf(-t, bv[i], c[j][i]);
    }
}

template<int K>
__device__ __forceinline__ void qr_all(float (&c)[4][16], float &prod, float &sgn) {
    qr_step<K>(c, prod, sgn);
    if constexpr (K < 14) qr_all<K + 1>(c, prod, sgn);
}

// SINGLE-WAVE BLOCKS, ZERO COUPLING: one wave = one sample; quad q = det q;
// each quad factorizes A then B (rolled m-loop, one QR body). No LDS, no
// __syncthreads anywhere. Cross-quad LSE via __shfl_xor over quad-index bits
// {4,8,16,32}: each lane accumulates exactly one representative per quad, so
// every det is counted once. Goal: VGPR <= 64 -> 8 waves/SIMD eligible ->
// issue capacity 6.5x oversubscribed vs wave lifetime -> VALU-bound floor.
__global__ __launch_bounds__(64) void logabssumdet_kernel(
    const float* __restrict__ a,
    const float* __restrict__ b,
    const float* __restrict__ w,
    float* __restrict__ out,
    int n_samples)
{
    const int tid   = threadIdx.x;      // 0..63
    const int lane4 = tid & 3;
    const int quad  = tid >> 2;         // det index 0..15
    // grid is sized exactly n_samples -> no bounds checks needed
    const size_t mat_off = ((size_t)blockIdx.x * NDET + quad) * (NDIM * NDIM);

    float x = 0.0f, sgn = 1.0f;

    #pragma unroll 1                    // ONE QR body in I-cache
    for (int m = 0; m < 2; ++m) {
        const float* src = m ? b : a;
        const float4* mb = reinterpret_cast<const float4*>(src + mat_off) + lane4;

        float c[4][16];
        #pragma unroll
        for (int i = 0; i < 16; ++i) {
            const float4 v = mb[i * 4];             // 64B contiguous per quad
            c[0][i] = v.x; c[1][i] = v.y; c[2][i] = v.z; c[3][i] = v.w;
        }

        float prod = 1.0f;                          // product of alpha_K (>0)
        qr_all<0>(c, prod, sgn);                    // 15 reflections
        prod *= bcast4f<3>(c[3][15]);               // column perm(15)=15 remainder

        x += __logf(fabsf(prod));                   // f32-range safe (proven)
        sgn = (prod < 0.0f) ? -sgn : sgn;
    }

    // ---- in-register LSE across the wave's 16 quads (no LDS, no barrier) --
    // reduce over quad-index bits only (offsets 4,8,16,32): each det once.
    float xmax = x;
    xmax = fmaxf(xmax, __shfl_xor(xmax, 4));
    xmax = fmaxf(xmax, __shfl_xor(xmax, 8));
    xmax = fmaxf(xmax, __shfl_xor(xmax, 16));
    xmax = fmaxf(xmax, __shfl_xor(xmax, 32));

    float term = sgn * __expf(x - xmax) * w[quad];
    term += __shfl_xor(term, 4);
    term += __shfl_xor(term, 8);
    term += __shfl_xor(term, 16);
    term += __shfl_xor(term, 32);

    if (tid == 0) {
        const int s = blockIdx.x;
        out[s] = __logf(fabsf(term)) + xmax;
        out[n_samples + s] = (term > 0.0f) ? 1.0f : ((term < 0.0f) ? -1.0f : 0.0f);
    }
}

extern "C" void kernel_launch(void* const* d_in, const int* in_sizes, int n_in,
                              void* d_out, int out_size, void* d_ws, size_t ws_size,
                              hipStream_t stream)
{
    const float* a = (const float*)d_in[0];
    const float* b = (const float*)d_in[1];
    const float* w = (const float*)d_in[2];
    float* out = (float*)d_out;

    const int n_samples = in_sizes[0] / (NDET * NDIM * NDIM);
    logabssumdet_kernel<<<n_samples, 64, 0, stream>>>(a, b, w, out, n_samples);
}